// Round 5
// baseline (108.965 us; speedup 1.0000x reference)
//
#include <hip/hip_runtime.h>

// sample_pdf (NeRF, det=True) — rank-scan gather formulation, no divergence.
//
// u_j=(2j+1)/256 fixed grid; g(c)=ceil((256c-1)/2)=#{j:u_j<c}. Interval
// k=[cdf[k],cdf[k+1]) owns sample slots [g_k,g_{k+1}), and
// K(j)=max{k: g_k<=j} == searchsorted(cdf,u_j,right)-1 (g_k<=j ⟺ cdf[k]<=u_j).
// Each lane: atomicMax its 2 interval indices at their start slots (ONLY if
// the start slot is < NS — an interval starting past the grid owns nothing;
// registering it was round-4's bug), store interval params at index k, then a
// 6-step wave max-scan recovers K(j) for all 128 slots; gather + lerp + store.

#define M     126   // weights per ray
#define NBINS 127   // bins per ray
#define NS    128   // samples per ray

__global__ __launch_bounds__(256) void sample_pdf_rank(
    const float* __restrict__ bins,
    const float* __restrict__ weights,
    float* __restrict__ out,
    int n_rays)
{
    __shared__ int   s_idx[4][NS];
    __shared__ float s_cl[4][NS];
    __shared__ float s_bl[4][NS];
    __shared__ float s_sl[4][NS];

    const int wave = threadIdx.x >> 6;
    const int lane = threadIdx.x & 63;
    const int ray  = blockIdx.x * 4 + wave;
    if (ray >= n_rays) return;

    const float* wrow = weights + (size_t)ray * M;
    const float* brow = bins    + (size_t)ray * NBINS;

    // ---- bins endpoints for intervals 2i (A) and 2i+1 (B) ----
    float b_a, b_b = 0.0f;
    if (lane < 63) {
        b_a = brow[2 * lane];          // bins[2i]
        b_b = brow[2 * lane + 1];      // bins[2i+1]
    } else {
        b_a = brow[126];               // feeds lane 62's b_c via shfl
    }
    const float b_c = __shfl_down(b_a, 1, 64);   // bins[2i+2]

    // ---- weights (+1e-5), lanes 0..62 cover all 126 ----
    float w0 = 0.0f, w1 = 0.0f;
    if (lane < 63) {
        float2 ww = *reinterpret_cast<const float2*>(wrow + 2 * lane);
        w0 = ww.x + 1e-5f;
        w1 = ww.y + 1e-5f;
    }
    const float pair = w0 + w1;

    // ---- wave inclusive scan of pair sums ----
    float ps = pair;
    #pragma unroll
    for (int off = 1; off < 64; off <<= 1) {
        float o = __shfl_up(ps, off, 64);
        if (lane >= off) ps += o;
    }
    const float total = __shfl(ps, 62, 64);
    const float inv   = 1.0f / total;

    // boundary cdf values; shared edges bitwise-shared via shfl
    const float c2 = ps * inv;                   // cdf[2i+2]
    float c0 = __shfl_up(c2, 1, 64);             // cdf[2i]
    if (lane == 0) c0 = 0.0f;
    const float c1 = (ps - pair + w0) * inv;     // cdf[2i+1] (owned)

    // ---- exact start slots g(c) = ceil((256c-1)*0.5) ----
    int g0 = (int)ceilf(fmaf(c0, 256.0f, -1.0f) * 0.5f);
    int g1 = (int)ceilf(fmaf(c1, 256.0f, -1.0f) * 0.5f);
    int kA = 2 * lane, kB = 2 * lane + 1;
    if (lane == 63) { g0 = NS; g1 = NS; }        // lane 63 owns no intervals
    g0 = max(g0, 0);
    g1 = max(g1, 0);

    // ---- per-interval slope ----
    float dA = c1 - c0; dA = (dA < 1e-5f) ? 1.0f : dA;
    float dB = c2 - c1; dB = (dB < 1e-5f) ? 1.0f : dB;
    const float slA = (b_b - b_a) * __builtin_amdgcn_rcpf(dA);
    const float slB = (b_c - b_b) * __builtin_amdgcn_rcpf(dB);

    // ---- phase 1: init + scatter (same-wave LDS is in-order) ----
    *reinterpret_cast<int2*>(&s_idx[wave][2 * lane]) = make_int2(0, 0);
    __builtin_amdgcn_wave_barrier();
    // Register ONLY intervals that start inside the sample grid. An interval
    // with g==NS owns no samples; writing it at slot NS-1 corrupts K(127).
    if (g0 < NS) atomicMax(&s_idx[wave][g0], kA);
    if (g1 < NS) atomicMax(&s_idx[wave][g1], kB);
    *reinterpret_cast<float2*>(&s_cl[wave][2 * lane]) = make_float2(c0, c1);
    *reinterpret_cast<float2*>(&s_bl[wave][2 * lane]) = make_float2(b_a, b_b);
    *reinterpret_cast<float2*>(&s_sl[wave][2 * lane]) = make_float2(slA, slB);
    __builtin_amdgcn_wave_barrier();

    // ---- phase 2: wave max-scan over the 128 slots ----
    const int2 xi = *reinterpret_cast<const int2*>(&s_idx[wave][2 * lane]);
    int m = max(xi.x, xi.y);
    #pragma unroll
    for (int off = 1; off < 64; off <<= 1) {
        int o = __shfl_up(m, off, 64);
        if (lane >= off) m = max(m, o);
    }
    int e = __shfl_up(m, 1, 64);
    if (lane == 0) e = 0;
    const int K0 = max(e, xi.x);        // interval of sample 2*lane
    const int K1 = max(K0, xi.y);       // interval of sample 2*lane+1

    // ---- phase 3: gather params, interpolate, store direct to global ----
    const float cl0 = s_cl[wave][K0], cl1 = s_cl[wave][K1];
    const float bl0 = s_bl[wave][K0], bl1 = s_bl[wave][K1];
    const float sl0 = s_sl[wave][K0], sl1 = s_sl[wave][K1];

    const float u0 = fmaf((float)lane, 0.015625f, 0.00390625f); // (4l+1)/256
    const float u1 = u0 + 0.0078125f;                           // (4l+3)/256
    float2 r;
    r.x = fmaf(u0 - cl0, sl0, bl0);
    r.y = fmaf(u1 - cl1, sl1, bl1);
    *reinterpret_cast<float2*>(out + (size_t)ray * NS + 2 * lane) = r;
}

extern "C" void kernel_launch(void* const* d_in, const int* in_sizes, int n_in,
                              void* d_out, int out_size, void* d_ws, size_t ws_size,
                              hipStream_t stream) {
    const float* bins    = (const float*)d_in[0];
    const float* weights = (const float*)d_in[1];
    float* out = (float*)d_out;

    const int n_rays = in_sizes[0] / NBINS;
    const int blocks = (n_rays + 3) / 4;
    sample_pdf_rank<<<blocks, 256, 0, stream>>>(bins, weights, out, n_rays);
}

// Round 6
// 87.809 us; speedup vs baseline: 1.2409x; 1.2409x over previous
//
#include <hip/hip_runtime.h>

// sample_pdf (NeRF, det=True) — rank-scan gather, DPP scans, 2 rays/wave.
//
// u_j=(2j+1)/256 fixed grid; g(c)=ceil((256c-1)/2)=#{j:u_j<c}. Interval
// k=[cdf[k],cdf[k+1]) owns sample slots [g_k,g_{k+1}); K(j)=max{k: g_k<=j}
// == searchsorted(cdf,u_j,right)-1. Each lane paints its 2 interval indices
// at their start slots (only if g<NS — an interval starting past the grid
// owns nothing), stores params (A,B) with sample = A + u*B, then a wave
// max-scan recovers K(j) for all slots; gather + fma + store.
// Boundary ulp disagreements only shift one sample to the adjacent interval
// (value-continuous, err <= ~1e-3 << 0.05 threshold) — no bitwise sharing.
//
// Scans: canonical GCN wave64 DPP scan (row_shr:1/2/4/8, row_bcast:15 to
// rows 1,3, row_bcast:31 to rows 2,3). Pure VALU — no LDS, no addr calc.

#define M     126
#define NBINS 127
#define NS    128
#define RPW   2     // rays per wave (ILP)

template<int CTRL, int RM>
__device__ __forceinline__ float dpp_f(float x) {
    return __builtin_bit_cast(float,
        __builtin_amdgcn_update_dpp(0, __builtin_bit_cast(int, x),
                                    CTRL, RM, 0xf, true));
}
template<int CTRL, int RM>
__device__ __forceinline__ int dpp_i(int x) {
    return __builtin_amdgcn_update_dpp(0, x, CTRL, RM, 0xf, true);
}

__device__ __forceinline__ float wave_iscan_add(float x) {
    x += dpp_f<0x111, 0xf>(x);   // row_shr:1
    x += dpp_f<0x112, 0xf>(x);   // row_shr:2
    x += dpp_f<0x114, 0xf>(x);   // row_shr:4
    x += dpp_f<0x118, 0xf>(x);   // row_shr:8
    x += dpp_f<0x142, 0xa>(x);   // row_bcast:15 -> rows 1,3
    x += dpp_f<0x143, 0xc>(x);   // row_bcast:31 -> rows 2,3
    return x;
}
__device__ __forceinline__ int wave_iscan_max(int x) {
    x = max(x, dpp_i<0x111, 0xf>(x));
    x = max(x, dpp_i<0x112, 0xf>(x));
    x = max(x, dpp_i<0x114, 0xf>(x));
    x = max(x, dpp_i<0x118, 0xf>(x));
    x = max(x, dpp_i<0x142, 0xa>(x));
    x = max(x, dpp_i<0x143, 0xc>(x));
    return x;
}

__global__ __launch_bounds__(256) void sample_pdf_rank2(
    const float* __restrict__ bins,
    const float* __restrict__ weights,
    float* __restrict__ out,
    int n_rays)
{
    __shared__ int   s_idx[4 * RPW][NS];
    __shared__ float s_A[4 * RPW][NS];   // A = bl - cl*sl
    __shared__ float s_B[4 * RPW][NS];   // B = sl

    const int wave = threadIdx.x >> 6;
    const int lane = threadIdx.x & 63;
    const int base = (blockIdx.x * 4 + wave) * RPW;

    bool  valid[RPW];
    float b_a[RPW], b_b[RPW], w0[RPW], w1[RPW];

    // ---- phase A: global loads (both rays in flight) + paint-slot init ----
    #pragma unroll
    for (int r = 0; r < RPW; ++r) {
        int ry = base + r;
        valid[r] = (ry < n_rays);
        if (!valid[r]) ry = 0;
        const float* wrow = weights + (size_t)ry * M;
        const float* brow = bins    + (size_t)ry * NBINS;
        if (lane < 63) {
            b_a[r] = brow[2 * lane];
            b_b[r] = brow[2 * lane + 1];
            float2 ww = *reinterpret_cast<const float2*>(wrow + 2 * lane);
            w0[r] = ww.x + 1e-5f;
            w1[r] = ww.y + 1e-5f;
        } else {
            b_a[r] = brow[126];          // feeds lane 62's b_c via shfl
            b_b[r] = 0.0f; w0[r] = 0.0f; w1[r] = 0.0f;
        }
        const int seg = wave * RPW + r;
        *reinterpret_cast<int2*>(&s_idx[seg][2 * lane]) = make_int2(0, 0);
    }
    __builtin_amdgcn_wave_barrier();

    // ---- phase B: scan -> cdf -> ranks -> params -> scatter ----
    #pragma unroll
    for (int r = 0; r < RPW; ++r) {
        const float b_c  = __shfl_down(b_a[r], 1, 64);     // bins[2i+2]
        const float pair = w0[r] + w1[r];
        const float ps   = wave_iscan_add(pair);           // inclusive prefix
        const float total = __shfl(ps, 63, 64);
        const float inv   = __builtin_amdgcn_rcpf(total);
        const float excl  = ps - pair;
        const float c0 = excl * inv;                       // cdf[2i]
        const float c1 = (excl + w0[r]) * inv;             // cdf[2i+1]
        const float c2 = ps * inv;                         // cdf[2i+2]

        int g0 = (int)ceilf(fmaf(c0, 256.0f, -1.0f) * 0.5f);
        int g1 = (int)ceilf(fmaf(c1, 256.0f, -1.0f) * 0.5f);
        if (lane == 63) { g0 = NS; g1 = NS; }              // owns no intervals
        g0 = max(g0, 0);
        g1 = max(g1, 0);

        float dA = c1 - c0; dA = (dA < 1e-5f) ? 1.0f : dA;
        float dB = c2 - c1; dB = (dB < 1e-5f) ? 1.0f : dB;
        const float slA = (b_b[r] - b_a[r]) * __builtin_amdgcn_rcpf(dA);
        const float slB = (b_c    - b_b[r]) * __builtin_amdgcn_rcpf(dB);
        const float A0  = fmaf(-c0, slA, b_a[r]);          // bl - cl*sl
        const float A1  = fmaf(-c1, slB, b_b[r]);

        const int seg = wave * RPW + r;
        *reinterpret_cast<float2*>(&s_A[seg][2 * lane]) = make_float2(A0, A1);
        *reinterpret_cast<float2*>(&s_B[seg][2 * lane]) = make_float2(slA, slB);
        if (g0 < NS) atomicMax(&s_idx[seg][g0], 2 * lane);
        if (g1 < NS) atomicMax(&s_idx[seg][g1], 2 * lane + 1);
    }
    __builtin_amdgcn_wave_barrier();

    // ---- phase C: max-scan K(j), gather, interpolate, store ----
    #pragma unroll
    for (int r = 0; r < RPW; ++r) {
        const int seg = wave * RPW + r;
        const int2 xi = *reinterpret_cast<const int2*>(&s_idx[seg][2 * lane]);
        int m = wave_iscan_max(max(xi.x, xi.y));
        int e = __shfl_up(m, 1, 64);
        if (lane == 0) e = 0;
        const int K0 = max(e, xi.x);        // interval of sample 2*lane
        const int K1 = max(K0, xi.y);       // interval of sample 2*lane+1

        const float A0 = s_A[seg][K0], B0 = s_B[seg][K0];
        const float A1 = s_A[seg][K1], B1 = s_B[seg][K1];
        const float u0 = fmaf((float)lane, 0.015625f, 0.00390625f); // (4l+1)/256
        const float u1 = u0 + 0.0078125f;                           // (4l+3)/256
        float2 res;
        res.x = fmaf(u0, B0, A0);
        res.y = fmaf(u1, B1, A1);
        if (valid[r])
            *reinterpret_cast<float2*>(out + (size_t)(base + r) * NS + 2 * lane) = res;
    }
}

extern "C" void kernel_launch(void* const* d_in, const int* in_sizes, int n_in,
                              void* d_out, int out_size, void* d_ws, size_t ws_size,
                              hipStream_t stream) {
    const float* bins    = (const float*)d_in[0];
    const float* weights = (const float*)d_in[1];
    float* out = (float*)d_out;

    const int n_rays = in_sizes[0] / NBINS;
    const int rays_per_block = 4 * RPW;
    const int blocks = (n_rays + rays_per_block - 1) / rays_per_block;
    sample_pdf_rank2<<<blocks, 256, 0, stream>>>(bins, weights, out, n_rays);
}